// Round 1
// baseline (561.571 us; speedup 1.0000x reference)
//
#include <hip/hip_runtime.h>

#define Bsz 2
#define Lq  2048
#define Dm  1024
#define Hh  16

typedef __attribute__((ext_vector_type(8))) short bf16x8;
typedef __attribute__((ext_vector_type(4))) float f32x4;

#define MFMA16(a, b, c) __builtin_amdgcn_mfma_f32_16x16x32_bf16((a), (b), (c), 0, 0, 0)

__device__ __forceinline__ short f2bf(float f) {
    union { float f; unsigned u; } v; v.f = f;
    unsigned r = v.u + 0x7fffu + ((v.u >> 16) & 1u);
    return (short)(r >> 16);
}

// async global->LDS, 16B per lane. LDS dest is wave-uniform base; HW appends lane*16.
__device__ __forceinline__ void gload16(const void* g, void* l) {
    __builtin_amdgcn_global_load_lds((const __attribute__((address_space(1))) void*)g,
                                     (__attribute__((address_space(3))) void*)l,
                                     16, 0, 0);
}

// ---------------- LayerNorm (fp32 in -> bf16 out) ----------------
__global__ __launch_bounds__(256) void ln_bf16(const float* __restrict__ x,
                                               const float* __restrict__ w,
                                               const float* __restrict__ b,
                                               short* __restrict__ out) {
    const int row = blockIdx.x;
    const int tid = threadIdx.x;
    const float4 v = ((const float4*)(x + (size_t)row * 1024))[tid];
    float s = v.x + v.y + v.z + v.w;
    float q = v.x * v.x + v.y * v.y + v.z * v.z + v.w * v.w;
    for (int off = 32; off > 0; off >>= 1) {
        s += __shfl_down(s, off);
        q += __shfl_down(q, off);
    }
    __shared__ float red[8];
    const int wave = tid >> 6;
    if ((tid & 63) == 0) { red[wave] = s; red[wave + 4] = q; }
    __syncthreads();
    s = red[0] + red[1] + red[2] + red[3];
    q = red[4] + red[5] + red[6] + red[7];
    const float mu = s * (1.0f / 1024.0f);
    const float var = q * (1.0f / 1024.0f) - mu * mu;
    const float rstd = rsqrtf(var + 1e-5f);
    const float4 wv = ((const float4*)w)[tid];
    const float4 bv = ((const float4*)b)[tid];
    short4 o;
    o.x = f2bf((v.x - mu) * rstd * wv.x + bv.x);
    o.y = f2bf((v.y - mu) * rstd * wv.y + bv.y);
    o.z = f2bf((v.z - mu) * rstd * wv.z + bv.z);
    o.w = f2bf((v.w - mu) * rstd * wv.w + bv.w);
    ((short4*)(out + (size_t)row * 1024))[tid] = o;
}

// ---------------- transpose + fp32->bf16: W[K][N] -> Wt[N][K] ----------------
__global__ __launch_bounds__(256) void tr_cvt(const float* __restrict__ W,
                                              short* __restrict__ Wt,
                                              int K, int N) {
    __shared__ float t[32][33];
    const int n0 = blockIdx.x * 32, k0 = blockIdx.y * 32;
    const int tx = threadIdx.x & 31, ty = threadIdx.x >> 5;  // ty 0..7
#pragma unroll
    for (int i = 0; i < 4; i++)
        t[ty + i * 8][tx] = W[(size_t)(k0 + ty + i * 8) * N + n0 + tx];
    __syncthreads();
#pragma unroll
    for (int i = 0; i < 4; i++)
        Wt[(size_t)(n0 + ty + i * 8) * K + k0 + tx] = f2bf(t[tx][ty + i * 8]);
}

// ---------------- GEMM: C[M][N] = A[M][K] * Bt[N][K]^T + bias, fused epilogues ----
// EP 0: QKV split -> q[B][H][L][64], k[B][H][L][64], vt[B][H][64][L] (bf16)
// EP 1: outf = res + C  (fp32)
// EP 2: outb = bf16(gelu_exact(C))
template <int EP>
__global__ __launch_bounds__(256, 2) void gemm_bt(
    const short* __restrict__ A, const short* __restrict__ Bt,
    const float* __restrict__ bias, int N, int K,
    short* __restrict__ qd, short* __restrict__ kd, short* __restrict__ vtd,
    const float* __restrict__ res, float* __restrict__ outf, short* __restrict__ outb) {
    __shared__ short As[128 * 32];
    __shared__ short Bs[128 * 32];
    const int tid = threadIdx.x;
    const int lane = tid & 63, w = tid >> 6;
    const int l16 = lane & 15, quad = lane >> 4;
    const int wr = (w & 1) * 64, wc = (w >> 1) * 64;
    const int row0 = blockIdx.y * 128, col0 = blockIdx.x * 128;
    const int srow = lane >> 2, scol = (lane & 3) * 8;

    f32x4 acc[4][4];
    const f32x4 z = {0.f, 0.f, 0.f, 0.f};
#pragma unroll
    for (int i = 0; i < 4; i++)
#pragma unroll
        for (int j = 0; j < 4; j++) acc[i][j] = z;

    const size_t arow = (size_t)(row0 + w * 32 + srow);
    const size_t brow = (size_t)(col0 + w * 32 + srow);

    for (int k0 = 0; k0 < K; k0 += 32) {
        gload16(A + arow * K + k0 + scol,        &As[(w * 32) * 32]);
        gload16(A + (arow + 16) * K + k0 + scol, &As[(w * 32 + 16) * 32]);
        gload16(Bt + brow * K + k0 + scol,        &Bs[(w * 32) * 32]);
        gload16(Bt + (brow + 16) * K + k0 + scol, &Bs[(w * 32 + 16) * 32]);
        __syncthreads();
        bf16x8 a[4], bb[4];
#pragma unroll
        for (int i = 0; i < 4; i++) a[i] = *(const bf16x8*)&As[(wr + i * 16 + l16) * 32 + quad * 8];
#pragma unroll
        for (int j = 0; j < 4; j++) bb[j] = *(const bf16x8*)&Bs[(wc + j * 16 + l16) * 32 + quad * 8];
#pragma unroll
        for (int i = 0; i < 4; i++)
#pragma unroll
            for (int j = 0; j < 4; j++) acc[i][j] = MFMA16(a[i], bb[j], acc[i][j]);
        __syncthreads();
    }

    float bz[4];
#pragma unroll
    for (int j = 0; j < 4; j++) bz[j] = bias[col0 + wc + j * 16 + l16];

#pragma unroll
    for (int i = 0; i < 4; i++) {
#pragma unroll
        for (int r = 0; r < 4; r++) {
            const int grow = row0 + wr + i * 16 + quad * 4 + r;
#pragma unroll
            for (int j = 0; j < 4; j++) {
                const int gcol = col0 + wc + j * 16 + l16;
                const float v = acc[i][j][r] + bz[j];
                if constexpr (EP == 0) {
                    const int b = grow >> 11, l = grow & 2047;
                    const int sec = gcol >> 10, wi = gcol & 1023;
                    const int h = wi >> 6, d = wi & 63;
                    if (sec == 2) {
                        vtd[(((size_t)b * Hh + h) * 64 + d) * Lq + l] = f2bf(v);
                    } else {
                        short* dst = sec ? kd : qd;
                        dst[(((size_t)b * Hh + h) * Lq + l) * 64 + d] = f2bf(v);
                    }
                } else if constexpr (EP == 1) {
                    outf[(size_t)grow * N + gcol] = res[(size_t)grow * N + gcol] + v;
                } else {
                    const float g = 0.5f * v * (1.0f + erff(v * 0.70710678118f));
                    outb[(size_t)grow * N + gcol] = f2bf(g);
                }
            }
        }
    }
}

// ---------------- causal flash attention ----------------
// Q,K: [B][H][L][64] bf16 ; Vt: [B][H][64][L] bf16 ; Y: [B][L][D] bf16
__global__ __launch_bounds__(256, 2) void attn_kernel(const short* __restrict__ Q,
                                                      const short* __restrict__ Kb,
                                                      const short* __restrict__ Vt,
                                                      short* __restrict__ Y) {
    const int bx = blockIdx.x, bh = blockIdx.y;
    const int tid = threadIdx.x;
    const int lane = tid & 63, wave = tid >> 6;
    const int l16 = lane & 15, quad = lane >> 4;
    const int qb = bx * 64 + wave * 16;

    const short* qg = Q + ((size_t)bh * Lq + qb) * 64;
    const bf16x8 aq0 = *(const bf16x8*)(qg + l16 * 64 + quad * 8);
    const bf16x8 aq1 = *(const bf16x8*)(qg + l16 * 64 + 32 + quad * 8);

    f32x4 o[4];
    const f32x4 z = {0.f, 0.f, 0.f, 0.f};
#pragma unroll
    for (int j = 0; j < 4; j++) o[j] = z;
    float m_i[4], l_i[4];
#pragma unroll
    for (int r = 0; r < 4; r++) { m_i[r] = -1e30f; l_i[r] = 0.f; }

    __shared__ short sP[4][16 * 40];
    short* myP = sP[wave];
    const short* kg = Kb + (size_t)bh * Lq * 64;
    const short* vg = Vt + (size_t)bh * 64 * Lq;
    const int nkt = 2 * (bx + 1);

    for (int kt = 0; kt < nkt; ++kt) {
        const int kb = kt * 32;
        const short* kp = kg + (size_t)kb * 64;
        const bf16x8 b00 = *(const bf16x8*)(kp + l16 * 64 + quad * 8);
        const bf16x8 b01 = *(const bf16x8*)(kp + l16 * 64 + 32 + quad * 8);
        const bf16x8 b10 = *(const bf16x8*)(kp + (16 + l16) * 64 + quad * 8);
        const bf16x8 b11 = *(const bf16x8*)(kp + (16 + l16) * 64 + 32 + quad * 8);
        f32x4 s0 = z, s1 = z;
        s0 = MFMA16(aq0, b00, s0);
        s0 = MFMA16(aq1, b01, s0);
        s1 = MFMA16(aq0, b10, s1);
        s1 = MFMA16(aq1, b11, s1);

        float p0[4], p1[4];
#pragma unroll
        for (int r = 0; r < 4; r++) {
            const int qi = qb + quad * 4 + r;
            float v0 = (kb + l16 <= qi) ? s0[r] * 0.03125f : -1e30f;
            float v1 = (kb + 16 + l16 <= qi) ? s1[r] * 0.03125f : -1e30f;
            float mr = fmaxf(v0, v1);
            mr = fmaxf(mr, __shfl_xor(mr, 1));
            mr = fmaxf(mr, __shfl_xor(mr, 2));
            mr = fmaxf(mr, __shfl_xor(mr, 4));
            mr = fmaxf(mr, __shfl_xor(mr, 8));
            const float mnew = fmaxf(m_i[r], mr);
            const float alpha = __expf(m_i[r] - mnew);
            v0 = __expf(v0 - mnew);
            v1 = __expf(v1 - mnew);
            float rs = v0 + v1;
            rs += __shfl_xor(rs, 1);
            rs += __shfl_xor(rs, 2);
            rs += __shfl_xor(rs, 4);
            rs += __shfl_xor(rs, 8);
            l_i[r] = l_i[r] * alpha + rs;
            m_i[r] = mnew;
            o[0][r] *= alpha; o[1][r] *= alpha; o[2][r] *= alpha; o[3][r] *= alpha;
            p0[r] = v0; p1[r] = v1;
        }
#pragma unroll
        for (int r = 0; r < 4; r++) {
            myP[(quad * 4 + r) * 40 + l16] = f2bf(p0[r]);
            myP[(quad * 4 + r) * 40 + 16 + l16] = f2bf(p1[r]);
        }
        __syncthreads();
        const bf16x8 pa = *(const bf16x8*)(myP + l16 * 40 + quad * 8);
        const short* vp = vg + kb;
#pragma unroll
        for (int j = 0; j < 4; j++) {
            const bf16x8 bv = *(const bf16x8*)(vp + (size_t)(j * 16 + l16) * Lq + quad * 8);
            o[j] = MFMA16(pa, bv, o[j]);
        }
        __syncthreads();
    }

    const int b = bh >> 4, h = bh & 15;
#pragma unroll
    for (int r = 0; r < 4; r++) {
        const float inv = 1.0f / l_i[r];
        const int qi = qb + quad * 4 + r;
        const size_t base = ((size_t)b * Lq + qi) * 1024 + h * 64;
        Y[base + l16]      = f2bf(o[0][r] * inv);
        Y[base + 16 + l16] = f2bf(o[1][r] * inv);
        Y[base + 32 + l16] = f2bf(o[2][r] * inv);
        Y[base + 48 + l16] = f2bf(o[3][r] * inv);
    }
}

extern "C" void kernel_launch(void* const* d_in, const int* in_sizes, int n_in,
                              void* d_out, int out_size, void* d_ws, size_t ws_size,
                              hipStream_t stream) {
    (void)in_sizes; (void)n_in; (void)out_size; (void)ws_size;
    const float* x     = (const float*)d_in[0];
    const float* ln1w  = (const float*)d_in[1];
    const float* ln1b  = (const float*)d_in[2];
    const float* ln2w  = (const float*)d_in[3];
    const float* ln2b  = (const float*)d_in[4];
    const float* attnw = (const float*)d_in[5];
    const float* attnb = (const float*)d_in[6];
    const float* projw = (const float*)d_in[7];
    const float* projb = (const float*)d_in[8];
    const float* fc1w  = (const float*)d_in[9];
    const float* fc1b  = (const float*)d_in[10];
    const float* fc2w  = (const float*)d_in[11];
    const float* fc2b  = (const float*)d_in[12];
    float* out = (float*)d_out;

    char* ws = (char*)d_ws;
    size_t off = 0;
    auto alloc = [&](size_t bytes) {
        void* p = ws + off;
        off += (bytes + 255) & ~(size_t)255;
        return p;
    };
    short* attnwT = (short*)alloc(3072ull * 1024 * 2);
    short* projwT = (short*)alloc(1024ull * 1024 * 2);
    short* fc1wT  = (short*)alloc(4096ull * 1024 * 2);
    short* fc2wT  = (short*)alloc(1024ull * 4096 * 2);
    short* hbuf   = (short*)alloc(4096ull * 1024 * 2);      // LN out (reused for LN2)
    short* qbuf   = (short*)alloc(4096ull * 1024 * 2);
    short* kbuf   = (short*)alloc(4096ull * 1024 * 2);
    short* vtbuf  = (short*)alloc(4096ull * 1024 * 2);
    short* ybuf   = (short*)alloc(4096ull * 1024 * 2);
    float* x1     = (float*)alloc(4096ull * 1024 * 4);
    short* hh = qbuf;  // q/k/vt/y are contiguous 32MB, dead after proj -> reuse for FC1 out

    // weights -> bf16 transposed
    tr_cvt<<<dim3(96, 32), 256, 0, stream>>>(attnw, attnwT, 1024, 3072);
    tr_cvt<<<dim3(32, 32), 256, 0, stream>>>(projw, projwT, 1024, 1024);
    tr_cvt<<<dim3(128, 32), 256, 0, stream>>>(fc1w, fc1wT, 1024, 4096);
    tr_cvt<<<dim3(32, 128), 256, 0, stream>>>(fc2w, fc2wT, 4096, 1024);

    // attention branch
    ln_bf16<<<4096, 256, 0, stream>>>(x, ln1w, ln1b, hbuf);
    gemm_bt<0><<<dim3(24, 32), 256, 0, stream>>>(hbuf, attnwT, attnb, 3072, 1024,
                                                 qbuf, kbuf, vtbuf, nullptr, nullptr, nullptr);
    attn_kernel<<<dim3(32, 32), 256, 0, stream>>>(qbuf, kbuf, vtbuf, ybuf);
    gemm_bt<1><<<dim3(8, 32), 256, 0, stream>>>(ybuf, projwT, projb, 1024, 1024,
                                                nullptr, nullptr, nullptr, x, x1, nullptr);

    // MLP branch
    ln_bf16<<<4096, 256, 0, stream>>>(x1, ln2w, ln2b, hbuf);
    gemm_bt<2><<<dim3(32, 32), 256, 0, stream>>>(hbuf, fc1wT, fc1b, 4096, 1024,
                                                 nullptr, nullptr, nullptr, nullptr, nullptr, hh);
    gemm_bt<1><<<dim3(8, 32), 256, 0, stream>>>(hh, fc2wT, fc2b, 1024, 4096,
                                                nullptr, nullptr, nullptr, x1, out, nullptr);
}

// Round 2
// 557.438 us; speedup vs baseline: 1.0074x; 1.0074x over previous
//
#include <hip/hip_runtime.h>

#define Bsz 2
#define Lq  2048
#define Dm  1024
#define Hh  16

typedef __attribute__((ext_vector_type(8))) short bf16x8;
typedef __attribute__((ext_vector_type(4))) float f32x4;

#define MFMA16(a, b, c) __builtin_amdgcn_mfma_f32_16x16x32_bf16((a), (b), (c), 0, 0, 0)
#define EXP2F(x) __builtin_amdgcn_exp2f(x)

__device__ __forceinline__ short f2bf(float f) {
    union { float f; unsigned u; } v; v.f = f;
    unsigned r = v.u + 0x7fffu + ((v.u >> 16) & 1u);
    return (short)(r >> 16);
}

// truncate-pack two fp32 -> packed bf16x2 (P values in [0,1]; trunc error ~2^-9 rel, fine)
__device__ __forceinline__ int pk2(float a, float b) {
    union { float f; unsigned u; } ua, ub; ua.f = a; ub.f = b;
    return (int)((ua.u >> 16) | (ub.u & 0xffff0000u));
}

// async global->LDS, 16B per lane. LDS dest is wave-uniform base; HW appends lane*16.
__device__ __forceinline__ void gload16(const void* g, void* l) {
    __builtin_amdgcn_global_load_lds((const __attribute__((address_space(1))) void*)g,
                                     (__attribute__((address_space(3))) void*)l,
                                     16, 0, 0);
}

// ---------------- LayerNorm (fp32 in -> bf16 out) ----------------
__global__ __launch_bounds__(256) void ln_bf16(const float* __restrict__ x,
                                               const float* __restrict__ w,
                                               const float* __restrict__ b,
                                               short* __restrict__ out) {
    const int row = blockIdx.x;
    const int tid = threadIdx.x;
    const float4 v = ((const float4*)(x + (size_t)row * 1024))[tid];
    float s = v.x + v.y + v.z + v.w;
    float q = v.x * v.x + v.y * v.y + v.z * v.z + v.w * v.w;
    for (int off = 32; off > 0; off >>= 1) {
        s += __shfl_down(s, off);
        q += __shfl_down(q, off);
    }
    __shared__ float red[8];
    const int wave = tid >> 6;
    if ((tid & 63) == 0) { red[wave] = s; red[wave + 4] = q; }
    __syncthreads();
    s = red[0] + red[1] + red[2] + red[3];
    q = red[4] + red[5] + red[6] + red[7];
    const float mu = s * (1.0f / 1024.0f);
    const float var = q * (1.0f / 1024.0f) - mu * mu;
    const float rstd = rsqrtf(var + 1e-5f);
    const float4 wv = ((const float4*)w)[tid];
    const float4 bv = ((const float4*)b)[tid];
    short4 o;
    o.x = f2bf((v.x - mu) * rstd * wv.x + bv.x);
    o.y = f2bf((v.y - mu) * rstd * wv.y + bv.y);
    o.z = f2bf((v.z - mu) * rstd * wv.z + bv.z);
    o.w = f2bf((v.w - mu) * rstd * wv.w + bv.w);
    ((short4*)(out + (size_t)row * 1024))[tid] = o;
}

// ---------------- transpose + fp32->bf16: W[K][N] -> Wt[N][K] ----------------
__global__ __launch_bounds__(256) void tr_cvt(const float* __restrict__ W,
                                              short* __restrict__ Wt,
                                              int K, int N) {
    __shared__ float t[32][33];
    const int n0 = blockIdx.x * 32, k0 = blockIdx.y * 32;
    const int tx = threadIdx.x & 31, ty = threadIdx.x >> 5;  // ty 0..7
#pragma unroll
    for (int i = 0; i < 4; i++)
        t[ty + i * 8][tx] = W[(size_t)(k0 + ty + i * 8) * N + n0 + tx];
    __syncthreads();
#pragma unroll
    for (int i = 0; i < 4; i++)
        Wt[(size_t)(n0 + ty + i * 8) * K + k0 + tx] = f2bf(t[tx][ty + i * 8]);
}

// ---------------- GEMM: C[M][N] = A[M][K] * Bt[N][K]^T + bias, fused epilogues ----
// EP 0: QKV split -> q[B][H][L][64], k[B][H][L][64], vt[B][H][64][L] (bf16)
// EP 1: outf = res + C  (fp32)
// EP 2: outb = bf16(gelu_exact(C))
template <int EP>
__global__ __launch_bounds__(256, 2) void gemm_bt(
    const short* __restrict__ A, const short* __restrict__ Bt,
    const float* __restrict__ bias, int N, int K,
    short* __restrict__ qd, short* __restrict__ kd, short* __restrict__ vtd,
    const float* __restrict__ res, float* __restrict__ outf, short* __restrict__ outb) {
    __shared__ short As[128 * 32];
    __shared__ short Bs[128 * 32];
    const int tid = threadIdx.x;
    const int lane = tid & 63, w = tid >> 6;
    const int l16 = lane & 15, quad = lane >> 4;
    const int wr = (w & 1) * 64, wc = (w >> 1) * 64;
    const int row0 = blockIdx.y * 128, col0 = blockIdx.x * 128;
    const int srow = lane >> 2, scol = (lane & 3) * 8;

    f32x4 acc[4][4];
    const f32x4 z = {0.f, 0.f, 0.f, 0.f};
#pragma unroll
    for (int i = 0; i < 4; i++)
#pragma unroll
        for (int j = 0; j < 4; j++) acc[i][j] = z;

    const size_t arow = (size_t)(row0 + w * 32 + srow);
    const size_t brow = (size_t)(col0 + w * 32 + srow);

    for (int k0 = 0; k0 < K; k0 += 32) {
        gload16(A + arow * K + k0 + scol,        &As[(w * 32) * 32]);
        gload16(A + (arow + 16) * K + k0 + scol, &As[(w * 32 + 16) * 32]);
        gload16(Bt + brow * K + k0 + scol,        &Bs[(w * 32) * 32]);
        gload16(Bt + (brow + 16) * K + k0 + scol, &Bs[(w * 32 + 16) * 32]);
        __syncthreads();
        bf16x8 a[4], bb[4];
#pragma unroll
        for (int i = 0; i < 4; i++) a[i] = *(const bf16x8*)&As[(wr + i * 16 + l16) * 32 + quad * 8];
#pragma unroll
        for (int j = 0; j < 4; j++) bb[j] = *(const bf16x8*)&Bs[(wc + j * 16 + l16) * 32 + quad * 8];
#pragma unroll
        for (int i = 0; i < 4; i++)
#pragma unroll
            for (int j = 0; j < 4; j++) acc[i][j] = MFMA16(a[i], bb[j], acc[i][j]);
        __syncthreads();
    }

    float bz[4];
#pragma unroll
    for (int j = 0; j < 4; j++) bz[j] = bias[col0 + wc + j * 16 + l16];

#pragma unroll
    for (int i = 0; i < 4; i++) {
#pragma unroll
        for (int r = 0; r < 4; r++) {
            const int grow = row0 + wr + i * 16 + quad * 4 + r;
#pragma unroll
            for (int j = 0; j < 4; j++) {
                const int gcol = col0 + wc + j * 16 + l16;
                const float v = acc[i][j][r] + bz[j];
                if constexpr (EP == 0) {
                    const int b = grow >> 11, l = grow & 2047;
                    const int sec = gcol >> 10, wi = gcol & 1023;
                    const int h = wi >> 6, d = wi & 63;
                    if (sec == 2) {
                        vtd[(((size_t)b * Hh + h) * 64 + d) * Lq + l] = f2bf(v);
                    } else {
                        short* dst = sec ? kd : qd;
                        dst[(((size_t)b * Hh + h) * Lq + l) * 64 + d] = f2bf(v);
                    }
                } else if constexpr (EP == 1) {
                    outf[(size_t)grow * N + gcol] = res[(size_t)grow * N + gcol] + v;
                } else {
                    const float g = 0.5f * v * (1.0f + erff(v * 0.70710678118f));
                    outb[(size_t)grow * N + gcol] = f2bf(g);
                }
            }
        }
    }
}

// ---------------- causal flash attention (S^T / O^T formulation) ----------------
// Q,K: [B][H][L][64] bf16 ; Vt: [B][H][64][L] bf16 ; Y: [B][L][D] bf16
// One wave per 16-query tile; no block barriers; softmax stats per query = l16,
// replicated across quads. Heavy tiles scheduled first for balance.
#define KP 72  // P row stride in shorts: 144B, 16B-aligned for all rows
__global__ __launch_bounds__(256) void attn_kernel(const short* __restrict__ Q,
                                                   const short* __restrict__ Kb,
                                                   const short* __restrict__ Vt,
                                                   short* __restrict__ Y) {
    const int tid = threadIdx.x;
    const int lane = tid & 63, wave = tid >> 6;
    const int l16 = lane & 15, quad = lane >> 4;
    const int qt = 127 - (blockIdx.x * 4 + wave);   // heavy-first
    const int bh = blockIdx.y;
    const int qb = qt * 16;

    const short* qg = Q + ((size_t)bh * Lq + qb) * 64;
    const short* kg = Kb + (size_t)bh * Lq * 64;
    const short* vg = Vt + (size_t)bh * 64 * Lq;

    __shared__ short sP[4][16 * KP];
    short* myP = sP[wave];
    short* wp = myP + l16 * KP;

    // Q as B-operand fragments (n=query=l16, k=dim)
    const bf16x8 qf0 = *(const bf16x8*)(qg + l16 * 64 + quad * 8);
    const bf16x8 qf1 = *(const bf16x8*)(qg + l16 * 64 + 32 + quad * 8);

    f32x4 o[4];
    const f32x4 z = {0.f, 0.f, 0.f, 0.f};
#pragma unroll
    for (int j = 0; j < 4; j++) o[j] = z;
    float m_i = -1e30f, l_i = 0.f;          // for query qb+l16 (replicated over quads)
    const float c1 = 0.0450842213f;         // (1/32) * log2(e)

    const int nf = qb >> 6;                 // full (unmasked) 64-key steps

    for (int s64 = 0; s64 < nf; ++s64) {
        const int kb = s64 * 64;
        const short* kp = kg + (size_t)kb * 64;
        // K as A-operand (m=key, k=dim): 4 key-subtiles x 2 dim-chunks
        bf16x8 kf[8];
#pragma unroll
        for (int kt = 0; kt < 4; kt++) {
            kf[2 * kt]     = *(const bf16x8*)(kp + (kt * 16 + l16) * 64 + quad * 8);
            kf[2 * kt + 1] = *(const bf16x8*)(kp + (kt * 16 + l16) * 64 + 32 + quad * 8);
        }
        f32x4 st[4];
#pragma unroll
        for (int kt = 0; kt < 4; kt++) {
            st[kt] = MFMA16(kf[2 * kt], qf0, z);
            st[kt] = MFMA16(kf[2 * kt + 1], qf1, st[kt]);
        }
        // V^T as A-operand for O^T (m=dim, k=key): issue early, consumed after softmax
        bf16x8 vf[8];
#pragma unroll
        for (int j = 0; j < 4; j++) {
            vf[2 * j]     = *(const bf16x8*)(vg + (size_t)(j * 16 + l16) * Lq + kb + quad * 8);
            vf[2 * j + 1] = *(const bf16x8*)(vg + (size_t)(j * 16 + l16) * Lq + kb + 32 + quad * 8);
        }
        // online softmax for query l16 over these 64 keys (16 vals/lane)
        float mx = st[0][0];
#pragma unroll
        for (int kt = 0; kt < 4; kt++)
#pragma unroll
            for (int r = 0; r < 4; r++) mx = fmaxf(mx, st[kt][r]);
        mx = fmaxf(mx, __shfl_xor(mx, 16));
        mx = fmaxf(mx, __shfl_xor(mx, 32));
        const float mnew = fmaxf(m_i, mx);
        const float alpha = EXP2F((m_i - mnew) * c1);
        const float nb = mnew * c1;
        float p[4][4], rs = 0.f;
#pragma unroll
        for (int kt = 0; kt < 4; kt++)
#pragma unroll
            for (int r = 0; r < 4; r++) {
                p[kt][r] = EXP2F(st[kt][r] * c1 - nb);
                rs += p[kt][r];
            }
        rs += __shfl_xor(rs, 16);
        rs += __shfl_xor(rs, 32);
        l_i = l_i * alpha + rs;
        m_i = mnew;
#pragma unroll
        for (int j = 0; j < 4; j++)
#pragma unroll
            for (int r = 0; r < 4; r++) o[j][r] *= alpha;
        // P^T transpose via LDS: 4x ds_write_b64 (4 consecutive keys per lane)
#pragma unroll
        for (int kt = 0; kt < 4; kt++) {
            int2 pw; pw.x = pk2(p[kt][0], p[kt][1]); pw.y = pk2(p[kt][2], p[kt][3]);
            *(int2*)(wp + kt * 16 + quad * 4) = pw;
        }
        const bf16x8 pf0 = *(const bf16x8*)(wp + quad * 8);
        const bf16x8 pf1 = *(const bf16x8*)(wp + 32 + quad * 8);
#pragma unroll
        for (int j = 0; j < 4; j++) {
            o[j] = MFMA16(vf[2 * j], pf0, o[j]);
            o[j] = MFMA16(vf[2 * j + 1], pf1, o[j]);
        }
    }

    // tail: masked 32-key steps covering [nf*64, qb+16)
    for (int kb = nf * 64; kb < qb + 16; kb += 32) {
        const short* kp = kg + (size_t)kb * 64;
        bf16x8 kf[4];
#pragma unroll
        for (int kt = 0; kt < 2; kt++) {
            kf[2 * kt]     = *(const bf16x8*)(kp + (kt * 16 + l16) * 64 + quad * 8);
            kf[2 * kt + 1] = *(const bf16x8*)(kp + (kt * 16 + l16) * 64 + 32 + quad * 8);
        }
        f32x4 st[2];
#pragma unroll
        for (int kt = 0; kt < 2; kt++) {
            st[kt] = MFMA16(kf[2 * kt], qf0, z);
            st[kt] = MFMA16(kf[2 * kt + 1], qf1, st[kt]);
        }
        bf16x8 vf[4];
#pragma unroll
        for (int j = 0; j < 4; j++)
            vf[j] = *(const bf16x8*)(vg + (size_t)(j * 16 + l16) * Lq + kb + quad * 8);
        float sv[2][4];
#pragma unroll
        for (int kt = 0; kt < 2; kt++)
#pragma unroll
            for (int r = 0; r < 4; r++) {
                const int krel = kb + kt * 16 + quad * 4 + r - qb;  // key - qb
                sv[kt][r] = (krel <= l16) ? st[kt][r] : -1e30f;
            }
        float mx = sv[0][0];
#pragma unroll
        for (int kt = 0; kt < 2; kt++)
#pragma unroll
            for (int r = 0; r < 4; r++) mx = fmaxf(mx, sv[kt][r]);
        mx = fmaxf(mx, __shfl_xor(mx, 16));
        mx = fmaxf(mx, __shfl_xor(mx, 32));
        const float mnew = fmaxf(m_i, mx);
        const float alpha = EXP2F((m_i - mnew) * c1);
        const float nb = mnew * c1;
        float p[2][4], rs = 0.f;
#pragma unroll
        for (int kt = 0; kt < 2; kt++)
#pragma unroll
            for (int r = 0; r < 4; r++) {
                p[kt][r] = EXP2F(sv[kt][r] * c1 - nb);
                rs += p[kt][r];
            }
        rs += __shfl_xor(rs, 16);
        rs += __shfl_xor(rs, 32);
        l_i = l_i * alpha + rs;
        m_i = mnew;
#pragma unroll
        for (int j = 0; j < 4; j++)
#pragma unroll
            for (int r = 0; r < 4; r++) o[j][r] *= alpha;
#pragma unroll
        for (int kt = 0; kt < 2; kt++) {
            int2 pw; pw.x = pk2(p[kt][0], p[kt][1]); pw.y = pk2(p[kt][2], p[kt][3]);
            *(int2*)(wp + kt * 16 + quad * 4) = pw;
        }
        const bf16x8 pf0 = *(const bf16x8*)(wp + quad * 8);
#pragma unroll
        for (int j = 0; j < 4; j++) o[j] = MFMA16(vf[j], pf0, o[j]);
    }

    // epilogue: O^T[dim][query] -> Y[b][q][h*64+dim]; stats already per query=l16
    const float inv = 1.0f / l_i;
    const int b = bh >> 4, h = bh & 15;
    const size_t base = ((size_t)b * Lq + qb + l16) * 1024 + h * 64;
#pragma unroll
    for (int j = 0; j < 4; j++) {
        short4 s4;
        s4.x = f2bf(o[j][0] * inv);
        s4.y = f2bf(o[j][1] * inv);
        s4.z = f2bf(o[j][2] * inv);
        s4.w = f2bf(o[j][3] * inv);
        *(short4*)(Y + base + j * 16 + quad * 4) = s4;
    }
}

extern "C" void kernel_launch(void* const* d_in, const int* in_sizes, int n_in,
                              void* d_out, int out_size, void* d_ws, size_t ws_size,
                              hipStream_t stream) {
    (void)in_sizes; (void)n_in; (void)out_size; (void)ws_size;
    const float* x     = (const float*)d_in[0];
    const float* ln1w  = (const float*)d_in[1];
    const float* ln1b  = (const float*)d_in[2];
    const float* ln2w  = (const float*)d_in[3];
    const float* ln2b  = (const float*)d_in[4];
    const float* attnw = (const float*)d_in[5];
    const float* attnb = (const float*)d_in[6];
    const float* projw = (const float*)d_in[7];
    const float* projb = (const float*)d_in[8];
    const float* fc1w  = (const float*)d_in[9];
    const float* fc1b  = (const float*)d_in[10];
    const float* fc2w  = (const float*)d_in[11];
    const float* fc2b  = (const float*)d_in[12];
    float* out = (float*)d_out;

    char* ws = (char*)d_ws;
    size_t off = 0;
    auto alloc = [&](size_t bytes) {
        void* p = ws + off;
        off += (bytes + 255) & ~(size_t)255;
        return p;
    };
    short* attnwT = (short*)alloc(3072ull * 1024 * 2);
    short* projwT = (short*)alloc(1024ull * 1024 * 2);
    short* fc1wT  = (short*)alloc(4096ull * 1024 * 2);
    short* fc2wT  = (short*)alloc(1024ull * 4096 * 2);
    short* hbuf   = (short*)alloc(4096ull * 1024 * 2);      // LN out (reused for LN2)
    short* qbuf   = (short*)alloc(4096ull * 1024 * 2);
    short* kbuf   = (short*)alloc(4096ull * 1024 * 2);
    short* vtbuf  = (short*)alloc(4096ull * 1024 * 2);
    short* ybuf   = (short*)alloc(4096ull * 1024 * 2);
    float* x1     = (float*)alloc(4096ull * 1024 * 4);
    short* hh = qbuf;  // q/k/vt/y are contiguous 32MB, dead after proj -> reuse for FC1 out

    // weights -> bf16 transposed
    tr_cvt<<<dim3(96, 32), 256, 0, stream>>>(attnw, attnwT, 1024, 3072);
    tr_cvt<<<dim3(32, 32), 256, 0, stream>>>(projw, projwT, 1024, 1024);
    tr_cvt<<<dim3(128, 32), 256, 0, stream>>>(fc1w, fc1wT, 1024, 4096);
    tr_cvt<<<dim3(32, 128), 256, 0, stream>>>(fc2w, fc2wT, 4096, 1024);

    // attention branch
    ln_bf16<<<4096, 256, 0, stream>>>(x, ln1w, ln1b, hbuf);
    gemm_bt<0><<<dim3(24, 32), 256, 0, stream>>>(hbuf, attnwT, attnb, 3072, 1024,
                                                 qbuf, kbuf, vtbuf, nullptr, nullptr, nullptr);
    attn_kernel<<<dim3(32, 32), 256, 0, stream>>>(qbuf, kbuf, vtbuf, ybuf);
    gemm_bt<1><<<dim3(8, 32), 256, 0, stream>>>(ybuf, projwT, projb, 1024, 1024,
                                                nullptr, nullptr, nullptr, x, x1, nullptr);

    // MLP branch
    ln_bf16<<<4096, 256, 0, stream>>>(x1, ln2w, ln2b, hbuf);
    gemm_bt<2><<<dim3(32, 32), 256, 0, stream>>>(hbuf, fc1wT, fc1b, 4096, 1024,
                                                 nullptr, nullptr, nullptr, nullptr, nullptr, hh);
    gemm_bt<1><<<dim3(8, 32), 256, 0, stream>>>(hh, fc2wT, fc2b, 1024, 4096,
                                                nullptr, nullptr, nullptr, x1, out, nullptr);
}

// Round 3
// 406.126 us; speedup vs baseline: 1.3828x; 1.3726x over previous
//
#include <hip/hip_runtime.h>

#define Bsz 2
#define Lq  2048
#define Dm  1024
#define Hh  16

typedef __attribute__((ext_vector_type(8))) short bf16x8;
typedef __attribute__((ext_vector_type(4))) float f32x4;

#define MFMA16(a, b, c) __builtin_amdgcn_mfma_f32_16x16x32_bf16((a), (b), (c), 0, 0, 0)
#define EXP2F(x) __builtin_amdgcn_exp2f(x)

__device__ __forceinline__ short f2bf(float f) {
    union { float f; unsigned u; } v; v.f = f;
    unsigned r = v.u + 0x7fffu + ((v.u >> 16) & 1u);
    return (short)(r >> 16);
}

// truncate-pack two fp32 -> packed bf16x2 (P values in [0,1]; trunc error ~2^-9 rel, fine)
__device__ __forceinline__ int pk2(float a, float b) {
    union { float f; unsigned u; } ua, ub; ua.f = a; ub.f = b;
    return (int)((ua.u >> 16) | (ub.u & 0xffff0000u));
}

// async global->LDS, 16B per lane. LDS dest is wave-uniform base; HW appends lane*16.
__device__ __forceinline__ void gload16(const void* g, void* l) {
    __builtin_amdgcn_global_load_lds((const __attribute__((address_space(1))) void*)g,
                                     (__attribute__((address_space(3))) void*)l,
                                     16, 0, 0);
}

// ---------------- LayerNorm (fp32 in -> bf16 out) ----------------
__global__ __launch_bounds__(256) void ln_bf16(const float* __restrict__ x,
                                               const float* __restrict__ w,
                                               const float* __restrict__ b,
                                               short* __restrict__ out) {
    const int row = blockIdx.x;
    const int tid = threadIdx.x;
    const float4 v = ((const float4*)(x + (size_t)row * 1024))[tid];
    float s = v.x + v.y + v.z + v.w;
    float q = v.x * v.x + v.y * v.y + v.z * v.z + v.w * v.w;
    for (int off = 32; off > 0; off >>= 1) {
        s += __shfl_down(s, off);
        q += __shfl_down(q, off);
    }
    __shared__ float red[8];
    const int wave = tid >> 6;
    if ((tid & 63) == 0) { red[wave] = s; red[wave + 4] = q; }
    __syncthreads();
    s = red[0] + red[1] + red[2] + red[3];
    q = red[4] + red[5] + red[6] + red[7];
    const float mu = s * (1.0f / 1024.0f);
    const float var = q * (1.0f / 1024.0f) - mu * mu;
    const float rstd = rsqrtf(var + 1e-5f);
    const float4 wv = ((const float4*)w)[tid];
    const float4 bv = ((const float4*)b)[tid];
    short4 o;
    o.x = f2bf((v.x - mu) * rstd * wv.x + bv.x);
    o.y = f2bf((v.y - mu) * rstd * wv.y + bv.y);
    o.z = f2bf((v.z - mu) * rstd * wv.z + bv.z);
    o.w = f2bf((v.w - mu) * rstd * wv.w + bv.w);
    ((short4*)(out + (size_t)row * 1024))[tid] = o;
}

// ---------------- transpose + fp32->bf16: W[K][N] -> Wt[N][K] ----------------
__global__ __launch_bounds__(256) void tr_cvt(const float* __restrict__ W,
                                              short* __restrict__ Wt,
                                              int K, int N) {
    __shared__ float t[32][33];
    const int n0 = blockIdx.x * 32, k0 = blockIdx.y * 32;
    const int tx = threadIdx.x & 31, ty = threadIdx.x >> 5;  // ty 0..7
#pragma unroll
    for (int i = 0; i < 4; i++)
        t[ty + i * 8][tx] = W[(size_t)(k0 + ty + i * 8) * N + n0 + tx];
    __syncthreads();
#pragma unroll
    for (int i = 0; i < 4; i++)
        Wt[(size_t)(n0 + ty + i * 8) * K + k0 + tx] = f2bf(t[tx][ty + i * 8]);
}

// ---------------- GEMM: C[M][N] = A[M][K] * Bt[N][K]^T + bias, fused epilogues ----
// EP 0: QKV split -> q[B][H][L][64], k[B][H][L][64], vt[B][H][64][L] (bf16)
// EP 1: outf = res + C  (fp32)
// EP 2: outb = bf16(gelu_exact(C))
template <int EP>
__global__ __launch_bounds__(256, 2) void gemm_bt(
    const short* __restrict__ A, const short* __restrict__ Bt,
    const float* __restrict__ bias, int N, int K,
    short* __restrict__ qd, short* __restrict__ kd, short* __restrict__ vtd,
    const float* __restrict__ res, float* __restrict__ outf, short* __restrict__ outb) {
    __shared__ short As[128 * 32];
    __shared__ short Bs[128 * 32];
    const int tid = threadIdx.x;
    const int lane = tid & 63, w = tid >> 6;
    const int l16 = lane & 15, quad = lane >> 4;
    const int wr = (w & 1) * 64, wc = (w >> 1) * 64;
    const int row0 = blockIdx.y * 128, col0 = blockIdx.x * 128;
    const int srow = lane >> 2, scol = (lane & 3) * 8;

    f32x4 acc[4][4];
    const f32x4 z = {0.f, 0.f, 0.f, 0.f};
#pragma unroll
    for (int i = 0; i < 4; i++)
#pragma unroll
        for (int j = 0; j < 4; j++) acc[i][j] = z;

    const size_t arow = (size_t)(row0 + w * 32 + srow);
    const size_t brow = (size_t)(col0 + w * 32 + srow);

    for (int k0 = 0; k0 < K; k0 += 32) {
        gload16(A + arow * K + k0 + scol,        &As[(w * 32) * 32]);
        gload16(A + (arow + 16) * K + k0 + scol, &As[(w * 32 + 16) * 32]);
        gload16(Bt + brow * K + k0 + scol,        &Bs[(w * 32) * 32]);
        gload16(Bt + (brow + 16) * K + k0 + scol, &Bs[(w * 32 + 16) * 32]);
        __syncthreads();
        bf16x8 a[4], bb[4];
#pragma unroll
        for (int i = 0; i < 4; i++) a[i] = *(const bf16x8*)&As[(wr + i * 16 + l16) * 32 + quad * 8];
#pragma unroll
        for (int j = 0; j < 4; j++) bb[j] = *(const bf16x8*)&Bs[(wc + j * 16 + l16) * 32 + quad * 8];
#pragma unroll
        for (int i = 0; i < 4; i++)
#pragma unroll
            for (int j = 0; j < 4; j++) acc[i][j] = MFMA16(a[i], bb[j], acc[i][j]);
        __syncthreads();
    }

    float bz[4];
#pragma unroll
    for (int j = 0; j < 4; j++) bz[j] = bias[col0 + wc + j * 16 + l16];

#pragma unroll
    for (int i = 0; i < 4; i++) {
#pragma unroll
        for (int r = 0; r < 4; r++) {
            const int grow = row0 + wr + i * 16 + quad * 4 + r;
#pragma unroll
            for (int j = 0; j < 4; j++) {
                const int gcol = col0 + wc + j * 16 + l16;
                const float v = acc[i][j][r] + bz[j];
                if constexpr (EP == 0) {
                    const int b = grow >> 11, l = grow & 2047;
                    const int sec = gcol >> 10, wi = gcol & 1023;
                    const int h = wi >> 6, d = wi & 63;
                    if (sec == 2) {
                        vtd[(((size_t)b * Hh + h) * 64 + d) * Lq + l] = f2bf(v);
                    } else {
                        short* dst = sec ? kd : qd;
                        dst[(((size_t)b * Hh + h) * Lq + l) * 64 + d] = f2bf(v);
                    }
                } else if constexpr (EP == 1) {
                    outf[(size_t)grow * N + gcol] = res[(size_t)grow * N + gcol] + v;
                } else {
                    const float g = 0.5f * v * (1.0f + erff(v * 0.70710678118f));
                    outb[(size_t)grow * N + gcol] = f2bf(g);
                }
            }
        }
    }
}

// ---------------- causal flash attention (block-cooperative, S^T/O^T) ----------------
// Q,K: [B][H][L][64] bf16 ; Vt: [B][H][64][L] bf16 ; Y: [B][L][D] bf16
// One block = (bh, 64 queries); 4 waves x 16 queries. 64-key steps staged into LDS
// via global_load_lds, shared by all 4 waves. K/V stored as two 64x32 half-tiles
// (64B rows) to keep fragment reads bank-conflict-minimal. All waves run qblk
// unmasked steps + 1 masked step (uniform trip count -> barriers legal).
#define KP 72  // P row stride in shorts (144B, 16B-aligned)
__global__ __launch_bounds__(256, 3) void attn_kernel(const short* __restrict__ Q,
                                                      const short* __restrict__ Kb,
                                                      const short* __restrict__ Vt,
                                                      short* __restrict__ Y) {
    const int tid = threadIdx.x;
    const int lane = tid & 63, wave = tid >> 6;
    const int l16 = lane & 15, quad = lane >> 4;
    const int qblk = 31 - blockIdx.x;              // heavy-first
    const int bh = blockIdx.y;
    const int qb = qblk * 64 + wave * 16;

    const short* qg = Q + ((size_t)bh * Lq + qb) * 64;
    const short* kg = Kb + (size_t)bh * Lq * 64;
    const short* vg = Vt + (size_t)bh * 64 * Lq;

    __shared__ short sK0[64 * 32], sK1[64 * 32];   // K dims 0..31 / 32..63, row=key
    __shared__ short sV0[64 * 32], sV1[64 * 32];   // V^T keys 0..31 / 32..63, row=dim
    __shared__ short sP[4][16 * KP];
    short* wp = sP[wave] + l16 * KP;

    // Q as B-operand fragments (n=query=l16, k=dim)
    const bf16x8 qf0 = *(const bf16x8*)(qg + l16 * 64 + quad * 8);
    const bf16x8 qf1 = *(const bf16x8*)(qg + l16 * 64 + 32 + quad * 8);

    f32x4 o[4];
    const f32x4 z = {0.f, 0.f, 0.f, 0.f};
#pragma unroll
    for (int j = 0; j < 4; j++) o[j] = z;
    float m_i = -1e30f, l_i = 0.f;                 // for query qb+l16 (replicated over quads)
    const float c1 = 0.0450842213f;                // (1/32) * log2(e)

    // staging lane mapping: 16 rows per gload16 (4 lanes x 16B cover a 64B half-row)
    const int srow = wave * 16 + (lane >> 2);      // row within 64-row tile
    const int scol = (lane & 3) * 8;               // shorts within 32-dim half
    const int nst = qblk + 1;

    for (int s = 0; s < nst; ++s) {
        const int kb = s * 64;
        gload16(kg + (size_t)(kb + srow) * 64 + scol,      &sK0[(wave * 16) * 32]);
        gload16(kg + (size_t)(kb + srow) * 64 + 32 + scol, &sK1[(wave * 16) * 32]);
        gload16(vg + (size_t)srow * Lq + kb + scol,        &sV0[(wave * 16) * 32]);
        gload16(vg + (size_t)srow * Lq + kb + 32 + scol,   &sV1[(wave * 16) * 32]);
        __syncthreads();

        // S^T = K * Q^T : K as A-operand (m=key, k=dim)
        f32x4 st[4];
#pragma unroll
        for (int kt = 0; kt < 4; kt++) {
            const bf16x8 k0 = *(const bf16x8*)&sK0[(kt * 16 + l16) * 32 + quad * 8];
            const bf16x8 k1 = *(const bf16x8*)&sK1[(kt * 16 + l16) * 32 + quad * 8];
            st[kt] = MFMA16(k0, qf0, z);
            st[kt] = MFMA16(k1, qf1, st[kt]);
        }

        if (s == nst - 1) {                        // masked step (keys qblk*64..+63)
#pragma unroll
            for (int kt = 0; kt < 4; kt++)
#pragma unroll
                for (int r = 0; r < 4; r++) {
                    const int krel = kt * 16 + quad * 4 + r - wave * 16;  // key - qb
                    if (krel > l16) st[kt][r] = -1e30f;
                }
        }

        // online softmax for query qb+l16 (16 vals/lane, replicated over quads)
        float mx = st[0][0];
#pragma unroll
        for (int kt = 0; kt < 4; kt++)
#pragma unroll
            for (int r = 0; r < 4; r++) mx = fmaxf(mx, st[kt][r]);
        mx = fmaxf(mx, __shfl_xor(mx, 16));
        mx = fmaxf(mx, __shfl_xor(mx, 32));
        const float mnew = fmaxf(m_i, mx);
        const float alpha = EXP2F((m_i - mnew) * c1);
        const float nb = mnew * c1;
        float p[4][4], rs = 0.f;
#pragma unroll
        for (int kt = 0; kt < 4; kt++)
#pragma unroll
            for (int r = 0; r < 4; r++) {
                p[kt][r] = EXP2F(st[kt][r] * c1 - nb);
                rs += p[kt][r];
            }
        rs += __shfl_xor(rs, 16);
        rs += __shfl_xor(rs, 32);
        l_i = l_i * alpha + rs;
        m_i = mnew;
#pragma unroll
        for (int j = 0; j < 4; j++)
#pragma unroll
            for (int r = 0; r < 4; r++) o[j][r] *= alpha;

        // P^T via LDS: lane owns 4 consecutive keys per kt -> 4x ds_write_b64
#pragma unroll
        for (int kt = 0; kt < 4; kt++) {
            int2 pw; pw.x = pk2(p[kt][0], p[kt][1]); pw.y = pk2(p[kt][2], p[kt][3]);
            *(int2*)(wp + kt * 16 + quad * 4) = pw;
        }
        const bf16x8 pf0 = *(const bf16x8*)(wp + quad * 8);
        const bf16x8 pf1 = *(const bf16x8*)(wp + 32 + quad * 8);
        // O^T += V^T * P^T : V^T as A-operand (m=dim, k=key)
#pragma unroll
        for (int j = 0; j < 4; j++) {
            const bf16x8 v0 = *(const bf16x8*)&sV0[(j * 16 + l16) * 32 + quad * 8];
            const bf16x8 v1 = *(const bf16x8*)&sV1[(j * 16 + l16) * 32 + quad * 8];
            o[j] = MFMA16(v0, pf0, o[j]);
            o[j] = MFMA16(v1, pf1, o[j]);
        }
        __syncthreads();
    }

    // epilogue: O^T[dim][query] -> Y[b][q][h*64+dim]
    const float inv = 1.0f / l_i;
    const int b = bh >> 4, h = bh & 15;
    const size_t base = ((size_t)b * Lq + qb + l16) * 1024 + h * 64;
#pragma unroll
    for (int j = 0; j < 4; j++) {
        short4 s4;
        s4.x = f2bf(o[j][0] * inv);
        s4.y = f2bf(o[j][1] * inv);
        s4.z = f2bf(o[j][2] * inv);
        s4.w = f2bf(o[j][3] * inv);
        *(short4*)(Y + base + j * 16 + quad * 4) = s4;
    }
}

extern "C" void kernel_launch(void* const* d_in, const int* in_sizes, int n_in,
                              void* d_out, int out_size, void* d_ws, size_t ws_size,
                              hipStream_t stream) {
    (void)in_sizes; (void)n_in; (void)out_size; (void)ws_size;
    const float* x     = (const float*)d_in[0];
    const float* ln1w  = (const float*)d_in[1];
    const float* ln1b  = (const float*)d_in[2];
    const float* ln2w  = (const float*)d_in[3];
    const float* ln2b  = (const float*)d_in[4];
    const float* attnw = (const float*)d_in[5];
    const float* attnb = (const float*)d_in[6];
    const float* projw = (const float*)d_in[7];
    const float* projb = (const float*)d_in[8];
    const float* fc1w  = (const float*)d_in[9];
    const float* fc1b  = (const float*)d_in[10];
    const float* fc2w  = (const float*)d_in[11];
    const float* fc2b  = (const float*)d_in[12];
    float* out = (float*)d_out;

    char* ws = (char*)d_ws;
    size_t off = 0;
    auto alloc = [&](size_t bytes) {
        void* p = ws + off;
        off += (bytes + 255) & ~(size_t)255;
        return p;
    };
    short* attnwT = (short*)alloc(3072ull * 1024 * 2);
    short* projwT = (short*)alloc(1024ull * 1024 * 2);
    short* fc1wT  = (short*)alloc(4096ull * 1024 * 2);
    short* fc2wT  = (short*)alloc(1024ull * 4096 * 2);
    short* hbuf   = (short*)alloc(4096ull * 1024 * 2);      // LN out (reused for LN2)
    short* qbuf   = (short*)alloc(4096ull * 1024 * 2);
    short* kbuf   = (short*)alloc(4096ull * 1024 * 2);
    short* vtbuf  = (short*)alloc(4096ull * 1024 * 2);
    short* ybuf   = (short*)alloc(4096ull * 1024 * 2);
    float* x1     = (float*)alloc(4096ull * 1024 * 4);
    short* hh = qbuf;  // q/k/vt/y are contiguous 32MB, dead after proj -> reuse for FC1 out

    // weights -> bf16 transposed
    tr_cvt<<<dim3(96, 32), 256, 0, stream>>>(attnw, attnwT, 1024, 3072);
    tr_cvt<<<dim3(32, 32), 256, 0, stream>>>(projw, projwT, 1024, 1024);
    tr_cvt<<<dim3(128, 32), 256, 0, stream>>>(fc1w, fc1wT, 1024, 4096);
    tr_cvt<<<dim3(32, 128), 256, 0, stream>>>(fc2w, fc2wT, 4096, 1024);

    // attention branch
    ln_bf16<<<4096, 256, 0, stream>>>(x, ln1w, ln1b, hbuf);
    gemm_bt<0><<<dim3(24, 32), 256, 0, stream>>>(hbuf, attnwT, attnb, 3072, 1024,
                                                 qbuf, kbuf, vtbuf, nullptr, nullptr, nullptr);
    attn_kernel<<<dim3(32, 32), 256, 0, stream>>>(qbuf, kbuf, vtbuf, ybuf);
    gemm_bt<1><<<dim3(8, 32), 256, 0, stream>>>(ybuf, projwT, projb, 1024, 1024,
                                                nullptr, nullptr, nullptr, x, x1, nullptr);

    // MLP branch
    ln_bf16<<<4096, 256, 0, stream>>>(x1, ln2w, ln2b, hbuf);
    gemm_bt<2><<<dim3(32, 32), 256, 0, stream>>>(hbuf, fc1wT, fc1b, 4096, 1024,
                                                 nullptr, nullptr, nullptr, nullptr, nullptr, hh);
    gemm_bt<1><<<dim3(8, 32), 256, 0, stream>>>(hh, fc2wT, fc2b, 1024, 4096,
                                                nullptr, nullptr, nullptr, x1, out, nullptr);
}

// Round 4
// 400.735 us; speedup vs baseline: 1.4014x; 1.0135x over previous
//
#include <hip/hip_runtime.h>

#define Bsz 2
#define Lq  2048
#define Dm  1024
#define Hh  16

typedef __attribute__((ext_vector_type(8))) short bf16x8;
typedef __attribute__((ext_vector_type(4))) float f32x4;

#define MFMA16(a, b, c) __builtin_amdgcn_mfma_f32_16x16x32_bf16((a), (b), (c), 0, 0, 0)
#define EXP2F(x) __builtin_amdgcn_exp2f(x)

__device__ __forceinline__ short f2bf(float f) {
    union { float f; unsigned u; } v; v.f = f;
    unsigned r = v.u + 0x7fffu + ((v.u >> 16) & 1u);
    return (short)(r >> 16);
}

__device__ __forceinline__ int pk2(float a, float b) {
    union { float f; unsigned u; } ua, ub; ua.f = a; ub.f = b;
    return (int)((ua.u >> 16) | (ub.u & 0xffff0000u));
}

// async global->LDS, 16B per lane. LDS dest is wave-uniform base; HW appends lane*16.
__device__ __forceinline__ void gload16(const void* g, void* l) {
    __builtin_amdgcn_global_load_lds((const __attribute__((address_space(1))) void*)g,
                                     (__attribute__((address_space(3))) void*)l,
                                     16, 0, 0);
}

// ---------------- LayerNorm (fp32 in -> bf16 out) ----------------
__global__ __launch_bounds__(256) void ln_bf16(const float* __restrict__ x,
                                               const float* __restrict__ w,
                                               const float* __restrict__ b,
                                               short* __restrict__ out) {
    const int row = blockIdx.x;
    const int tid = threadIdx.x;
    const float4 v = ((const float4*)(x + (size_t)row * 1024))[tid];
    float s = v.x + v.y + v.z + v.w;
    float q = v.x * v.x + v.y * v.y + v.z * v.z + v.w * v.w;
    for (int off = 32; off > 0; off >>= 1) {
        s += __shfl_down(s, off);
        q += __shfl_down(q, off);
    }
    __shared__ float red[8];
    const int wave = tid >> 6;
    if ((tid & 63) == 0) { red[wave] = s; red[wave + 4] = q; }
    __syncthreads();
    s = red[0] + red[1] + red[2] + red[3];
    q = red[4] + red[5] + red[6] + red[7];
    const float mu = s * (1.0f / 1024.0f);
    const float var = q * (1.0f / 1024.0f) - mu * mu;
    const float rstd = rsqrtf(var + 1e-5f);
    const float4 wv = ((const float4*)w)[tid];
    const float4 bv = ((const float4*)b)[tid];
    short4 o;
    o.x = f2bf((v.x - mu) * rstd * wv.x + bv.x);
    o.y = f2bf((v.y - mu) * rstd * wv.y + bv.y);
    o.z = f2bf((v.z - mu) * rstd * wv.z + bv.z);
    o.w = f2bf((v.w - mu) * rstd * wv.w + bv.w);
    ((short4*)(out + (size_t)row * 1024))[tid] = o;
}

// ---------------- transpose + fp32->bf16: W[K][N] -> Wt[N][K] ----------------
__global__ __launch_bounds__(256) void tr_cvt(const float* __restrict__ W,
                                              short* __restrict__ Wt,
                                              int K, int N) {
    __shared__ float t[32][33];
    const int n0 = blockIdx.x * 32, k0 = blockIdx.y * 32;
    const int tx = threadIdx.x & 31, ty = threadIdx.x >> 5;  // ty 0..7
#pragma unroll
    for (int i = 0; i < 4; i++)
        t[ty + i * 8][tx] = W[(size_t)(k0 + ty + i * 8) * N + n0 + tx];
    __syncthreads();
#pragma unroll
    for (int i = 0; i < 4; i++)
        Wt[(size_t)(n0 + ty + i * 8) * K + k0 + tx] = f2bf(t[tx][ty + i * 8]);
}

// ---------------- GEMM (wide): C = A * Bt^T + bias, fused epilogues ----------------
// EP 0: QKV split -> q[B][H][L][64], k[B][H][L][64], vt[B][H][64][L] (bf16)
// EP 2: outb = bf16(gelu_exact(C))
template <int EP>
__global__ __launch_bounds__(256, 2) void gemm_bt(
    const short* __restrict__ A, const short* __restrict__ Bt,
    const float* __restrict__ bias, int N, int K,
    short* __restrict__ qd, short* __restrict__ kd, short* __restrict__ vtd,
    short* __restrict__ outb) {
    __shared__ short As[128 * 32];
    __shared__ short Bs[128 * 32];
    const int tid = threadIdx.x;
    const int lane = tid & 63, w = tid >> 6;
    const int l16 = lane & 15, quad = lane >> 4;
    const int wr = (w & 1) * 64, wc = (w >> 1) * 64;
    const int row0 = blockIdx.y * 128, col0 = blockIdx.x * 128;
    const int srow = lane >> 2, scol = (lane & 3) * 8;

    f32x4 acc[4][4];
    const f32x4 z = {0.f, 0.f, 0.f, 0.f};
#pragma unroll
    for (int i = 0; i < 4; i++)
#pragma unroll
        for (int j = 0; j < 4; j++) acc[i][j] = z;

    const size_t arow = (size_t)(row0 + w * 32 + srow);
    const size_t brow = (size_t)(col0 + w * 32 + srow);

    for (int k0 = 0; k0 < K; k0 += 32) {
        gload16(A + arow * K + k0 + scol,        &As[(w * 32) * 32]);
        gload16(A + (arow + 16) * K + k0 + scol, &As[(w * 32 + 16) * 32]);
        gload16(Bt + brow * K + k0 + scol,        &Bs[(w * 32) * 32]);
        gload16(Bt + (brow + 16) * K + k0 + scol, &Bs[(w * 32 + 16) * 32]);
        __syncthreads();
        bf16x8 a[4], bb[4];
#pragma unroll
        for (int i = 0; i < 4; i++) a[i] = *(const bf16x8*)&As[(wr + i * 16 + l16) * 32 + quad * 8];
#pragma unroll
        for (int j = 0; j < 4; j++) bb[j] = *(const bf16x8*)&Bs[(wc + j * 16 + l16) * 32 + quad * 8];
#pragma unroll
        for (int i = 0; i < 4; i++)
#pragma unroll
            for (int j = 0; j < 4; j++) acc[i][j] = MFMA16(a[i], bb[j], acc[i][j]);
        __syncthreads();
    }

    float bz[4];
#pragma unroll
    for (int j = 0; j < 4; j++) bz[j] = bias[col0 + wc + j * 16 + l16];

#pragma unroll
    for (int i = 0; i < 4; i++) {
#pragma unroll
        for (int r = 0; r < 4; r++) {
            const int grow = row0 + wr + i * 16 + quad * 4 + r;
#pragma unroll
            for (int j = 0; j < 4; j++) {
                const int gcol = col0 + wc + j * 16 + l16;
                const float v = acc[i][j][r] + bz[j];
                if constexpr (EP == 0) {
                    const int b = grow >> 11, l = grow & 2047;
                    const int sec = gcol >> 10, wi = gcol & 1023;
                    const int h = wi >> 6, d = wi & 63;
                    if (sec == 2) {
                        vtd[(((size_t)b * Hh + h) * 64 + d) * Lq + l] = f2bf(v);
                    } else {
                        short* dst = sec ? kd : qd;
                        dst[(((size_t)b * Hh + h) * Lq + l) * 64 + d] = f2bf(v);
                    }
                } else {
                    const float g = 0.5f * v * (1.0f + erff(v * 0.70710678118f));
                    outb[(size_t)grow * N + gcol] = f2bf(g);
                }
            }
        }
    }
}

// ---------------- skinny GEMM (N=1024, 256 blocks = 1/CU): ring-4 pipeline ----------
// out = res + A*Bt^T + bias (fp32 out). BK=32, 4 LDS buffers, depth-3 prefetch,
// fine-grained vmcnt (never 0 in steady state) + raw s_barrier. XCD-swizzled so
// each XCD owns 4 row-bands x all 8 col-blocks (A fetched once per XCD).
__global__ __launch_bounds__(256, 1) void gemm_skinny(
    const short* __restrict__ A, const short* __restrict__ Bt,
    const float* __restrict__ bias, int K,
    const float* __restrict__ res, float* __restrict__ outf) {
    __shared__ short As[4][128 * 32];
    __shared__ short Bs[4][128 * 32];
    const int tid = threadIdx.x;
    const int lane = tid & 63, w = tid >> 6;
    const int l16 = lane & 15, quad = lane >> 4;
    const int wr = (w & 1) * 64, wc = (w >> 1) * 64;
    // swizzle: XCD x (= n%8) owns row-bands 4x..4x+3, all 8 col-blocks
    const int n = blockIdx.x;
    const int x = n & 7, t = n >> 3;
    const int row0 = (x * 4 + (t & 3)) * 128, col0 = (t >> 2) * 128;
    const int srow = lane >> 2, scol = (lane & 3) * 8;
    const size_t arow = (size_t)(row0 + w * 32 + srow);
    const size_t brow = (size_t)(col0 + w * 32 + srow);
    const int niter = K >> 5;

    f32x4 acc[4][4];
    const f32x4 z = {0.f, 0.f, 0.f, 0.f};
#pragma unroll
    for (int i = 0; i < 4; i++)
#pragma unroll
        for (int j = 0; j < 4; j++) acc[i][j] = z;

    auto stage = [&](int it) {
        const int k0 = it << 5;
        const int b = it & 3;
        gload16(A + arow * K + k0 + scol,        &As[b][(w * 32) * 32]);
        gload16(A + (arow + 16) * K + k0 + scol, &As[b][(w * 32 + 16) * 32]);
        gload16(Bt + brow * K + k0 + scol,        &Bs[b][(w * 32) * 32]);
        gload16(Bt + (brow + 16) * K + k0 + scol, &Bs[b][(w * 32 + 16) * 32]);
    };

    stage(0);
    stage(1);
    stage(2);

    for (int i = 0; i < niter; ++i) {
        // per-wave: 4 loads/iter in flight per staged iter. Ensure iter-i's done.
        if (i + 2 < niter)      asm volatile("s_waitcnt vmcnt(8)" ::: "memory");
        else if (i + 1 < niter) asm volatile("s_waitcnt vmcnt(4)" ::: "memory");
        else                    asm volatile("s_waitcnt vmcnt(0)" ::: "memory");
        asm volatile("s_barrier" ::: "memory");
        if (i + 3 < niter) stage(i + 3);   // overwrites buf read at iter i-1 (all waves past barrier)
        const int b = i & 3;
        bf16x8 a[4], bb[4];
#pragma unroll
        for (int ii = 0; ii < 4; ii++) a[ii] = *(const bf16x8*)&As[b][(wr + ii * 16 + l16) * 32 + quad * 8];
#pragma unroll
        for (int j = 0; j < 4; j++) bb[j] = *(const bf16x8*)&Bs[b][(wc + j * 16 + l16) * 32 + quad * 8];
#pragma unroll
        for (int ii = 0; ii < 4; ii++)
#pragma unroll
            for (int j = 0; j < 4; j++) acc[ii][j] = MFMA16(a[ii], bb[j], acc[ii][j]);
    }

    float bz[4];
#pragma unroll
    for (int j = 0; j < 4; j++) bz[j] = bias[col0 + wc + j * 16 + l16];

#pragma unroll
    for (int i = 0; i < 4; i++) {
#pragma unroll
        for (int r = 0; r < 4; r++) {
            const int grow = row0 + wr + i * 16 + quad * 4 + r;
#pragma unroll
            for (int j = 0; j < 4; j++) {
                const int gcol = col0 + wc + j * 16 + l16;
                const float v = acc[i][j][r] + bz[j];
                outf[(size_t)grow * 1024 + gcol] = res[(size_t)grow * 1024 + gcol] + v;
            }
        }
    }
}

// ---------------- causal flash attention (block-cooperative, S^T/O^T) ----------------
#define KP 72  // P row stride in shorts (144B, 16B-aligned)
__global__ __launch_bounds__(256, 3) void attn_kernel(const short* __restrict__ Q,
                                                      const short* __restrict__ Kb,
                                                      const short* __restrict__ Vt,
                                                      short* __restrict__ Y) {
    const int tid = threadIdx.x;
    const int lane = tid & 63, wave = tid >> 6;
    const int l16 = lane & 15, quad = lane >> 4;
    const int qblk = 31 - blockIdx.x;              // heavy-first
    const int bh = blockIdx.y;
    const int qb = qblk * 64 + wave * 16;

    const short* qg = Q + ((size_t)bh * Lq + qb) * 64;
    const short* kg = Kb + (size_t)bh * Lq * 64;
    const short* vg = Vt + (size_t)bh * 64 * Lq;

    __shared__ short sK0[64 * 32], sK1[64 * 32];   // K dims 0..31 / 32..63, row=key
    __shared__ short sV0[64 * 32], sV1[64 * 32];   // V^T keys 0..31 / 32..63, row=dim
    __shared__ short sP[4][16 * KP];
    short* wp = sP[wave] + l16 * KP;

    const bf16x8 qf0 = *(const bf16x8*)(qg + l16 * 64 + quad * 8);
    const bf16x8 qf1 = *(const bf16x8*)(qg + l16 * 64 + 32 + quad * 8);

    f32x4 o[4];
    const f32x4 z = {0.f, 0.f, 0.f, 0.f};
#pragma unroll
    for (int j = 0; j < 4; j++) o[j] = z;
    float m_i = -1e30f, l_i = 0.f;
    const float c1 = 0.0450842213f;                // (1/32) * log2(e)

    const int srow = wave * 16 + (lane >> 2);
    const int scol = (lane & 3) * 8;
    const int nst = qblk + 1;

    for (int s = 0; s < nst; ++s) {
        const int kb = s * 64;
        gload16(kg + (size_t)(kb + srow) * 64 + scol,      &sK0[(wave * 16) * 32]);
        gload16(kg + (size_t)(kb + srow) * 64 + 32 + scol, &sK1[(wave * 16) * 32]);
        gload16(vg + (size_t)srow * Lq + kb + scol,        &sV0[(wave * 16) * 32]);
        gload16(vg + (size_t)srow * Lq + kb + 32 + scol,   &sV1[(wave * 16) * 32]);
        __syncthreads();

        f32x4 st[4];
#pragma unroll
        for (int kt = 0; kt < 4; kt++) {
            const bf16x8 k0 = *(const bf16x8*)&sK0[(kt * 16 + l16) * 32 + quad * 8];
            const bf16x8 k1 = *(const bf16x8*)&sK1[(kt * 16 + l16) * 32 + quad * 8];
            st[kt] = MFMA16(k0, qf0, z);
            st[kt] = MFMA16(k1, qf1, st[kt]);
        }

        if (s == nst - 1) {
#pragma unroll
            for (int kt = 0; kt < 4; kt++)
#pragma unroll
                for (int r = 0; r < 4; r++) {
                    const int krel = kt * 16 + quad * 4 + r - wave * 16;
                    if (krel > l16) st[kt][r] = -1e30f;
                }
        }

        float mx = st[0][0];
#pragma unroll
        for (int kt = 0; kt < 4; kt++)
#pragma unroll
            for (int r = 0; r < 4; r++) mx = fmaxf(mx, st[kt][r]);
        mx = fmaxf(mx, __shfl_xor(mx, 16));
        mx = fmaxf(mx, __shfl_xor(mx, 32));
        const float mnew = fmaxf(m_i, mx);
        const float alpha = EXP2F((m_i - mnew) * c1);
        const float nb = mnew * c1;
        float p[4][4], rs = 0.f;
#pragma unroll
        for (int kt = 0; kt < 4; kt++)
#pragma unroll
            for (int r = 0; r < 4; r++) {
                p[kt][r] = EXP2F(st[kt][r] * c1 - nb);
                rs += p[kt][r];
            }
        rs += __shfl_xor(rs, 16);
        rs += __shfl_xor(rs, 32);
        l_i = l_i * alpha + rs;
        m_i = mnew;
#pragma unroll
        for (int j = 0; j < 4; j++)
#pragma unroll
            for (int r = 0; r < 4; r++) o[j][r] *= alpha;

#pragma unroll
        for (int kt = 0; kt < 4; kt++) {
            int2 pw; pw.x = pk2(p[kt][0], p[kt][1]); pw.y = pk2(p[kt][2], p[kt][3]);
            *(int2*)(wp + kt * 16 + quad * 4) = pw;
        }
        const bf16x8 pf0 = *(const bf16x8*)(wp + quad * 8);
        const bf16x8 pf1 = *(const bf16x8*)(wp + 32 + quad * 8);
#pragma unroll
        for (int j = 0; j < 4; j++) {
            const bf16x8 v0 = *(const bf16x8*)&sV0[(j * 16 + l16) * 32 + quad * 8];
            const bf16x8 v1 = *(const bf16x8*)&sV1[(j * 16 + l16) * 32 + quad * 8];
            o[j] = MFMA16(v0, pf0, o[j]);
            o[j] = MFMA16(v1, pf1, o[j]);
        }
        __syncthreads();
    }

    const float inv = 1.0f / l_i;
    const int b = bh >> 4, h = bh & 15;
    const size_t base = ((size_t)b * Lq + qb + l16) * 1024 + h * 64;
#pragma unroll
    for (int j = 0; j < 4; j++) {
        short4 s4;
        s4.x = f2bf(o[j][0] * inv);
        s4.y = f2bf(o[j][1] * inv);
        s4.z = f2bf(o[j][2] * inv);
        s4.w = f2bf(o[j][3] * inv);
        *(short4*)(Y + base + j * 16 + quad * 4) = s4;
    }
}

extern "C" void kernel_launch(void* const* d_in, const int* in_sizes, int n_in,
                              void* d_out, int out_size, void* d_ws, size_t ws_size,
                              hipStream_t stream) {
    (void)in_sizes; (void)n_in; (void)out_size; (void)ws_size;
    const float* x     = (const float*)d_in[0];
    const float* ln1w  = (const float*)d_in[1];
    const float* ln1b  = (const float*)d_in[2];
    const float* ln2w  = (const float*)d_in[3];
    const float* ln2b  = (const float*)d_in[4];
    const float* attnw = (const float*)d_in[5];
    const float* attnb = (const float*)d_in[6];
    const float* projw = (const float*)d_in[7];
    const float* projb = (const float*)d_in[8];
    const float* fc1w  = (const float*)d_in[9];
    const float* fc1b  = (const float*)d_in[10];
    const float* fc2w  = (const float*)d_in[11];
    const float* fc2b  = (const float*)d_in[12];
    float* out = (float*)d_out;

    char* ws = (char*)d_ws;
    size_t off = 0;
    auto alloc = [&](size_t bytes) {
        void* p = ws + off;
        off += (bytes + 255) & ~(size_t)255;
        return p;
    };
    short* attnwT = (short*)alloc(3072ull * 1024 * 2);
    short* projwT = (short*)alloc(1024ull * 1024 * 2);
    short* fc1wT  = (short*)alloc(4096ull * 1024 * 2);
    short* fc2wT  = (short*)alloc(1024ull * 4096 * 2);
    short* hbuf   = (short*)alloc(4096ull * 1024 * 2);      // LN out (reused for LN2)
    short* qbuf   = (short*)alloc(4096ull * 1024 * 2);
    short* kbuf   = (short*)alloc(4096ull * 1024 * 2);
    short* vtbuf  = (short*)alloc(4096ull * 1024 * 2);
    short* ybuf   = (short*)alloc(4096ull * 1024 * 2);
    float* x1     = (float*)alloc(4096ull * 1024 * 4);
    short* hh = qbuf;  // q/k/vt/y are contiguous 32MB, dead after proj -> reuse for FC1 out

    // weights -> bf16 transposed
    tr_cvt<<<dim3(96, 32), 256, 0, stream>>>(attnw, attnwT, 1024, 3072);
    tr_cvt<<<dim3(32, 32), 256, 0, stream>>>(projw, projwT, 1024, 1024);
    tr_cvt<<<dim3(128, 32), 256, 0, stream>>>(fc1w, fc1wT, 1024, 4096);
    tr_cvt<<<dim3(32, 128), 256, 0, stream>>>(fc2w, fc2wT, 4096, 1024);

    // attention branch
    ln_bf16<<<4096, 256, 0, stream>>>(x, ln1w, ln1b, hbuf);
    gemm_bt<0><<<dim3(24, 32), 256, 0, stream>>>(hbuf, attnwT, attnb, 3072, 1024,
                                                 qbuf, kbuf, vtbuf, nullptr);
    attn_kernel<<<dim3(32, 32), 256, 0, stream>>>(qbuf, kbuf, vtbuf, ybuf);
    gemm_skinny<<<256, 256, 0, stream>>>(ybuf, projwT, projb, 1024, x, x1);

    // MLP branch
    ln_bf16<<<4096, 256, 0, stream>>>(x1, ln2w, ln2b, hbuf);
    gemm_bt<2><<<dim3(32, 32), 256, 0, stream>>>(hbuf, fc1wT, fc1b, 4096, 1024,
                                                 nullptr, nullptr, nullptr, hh);
    gemm_skinny<<<256, 256, 0, stream>>>(hh, fc2wT, fc2b, 4096, x1, out);
}